// Round 8
// baseline (154.126 us; speedup 1.0000x reference)
//
#include <hip/hip_runtime.h>
#include <math.h>

// ---------------- problem constants ----------------
#define NS 3000          // 30*100 samples
#define NF 147           // 3*7*7 encoder feats
#define ND 512
#define NSIG 49          // 7x7 shift classes
#define NSAMP 12         // samples per k_S block
#define NSBLK 250        // 3000 / 12

// ---------------- ws layout (float offsets) ----------------
#define OFF_WT     0            // 6272 (7*224 float4: w0,w1,i0,i1)
#define OFF_FEATS  6272         // 147 -> pad 160
#define OFF_HSN    6432         // 1  -> pad 16
#define OFF_WW     6448         // 147*147 = 21609 -> pad to 28064
#define OFF_WSTAR  28064        // 147 -> pad 160
#define OFF_V      28224        // 7*3*224*49 = 230496 -> 258720
#define OFF_T      258720       // T2[sig][g][f]: 49*49*147 = 352947 -> 611667
#define OFF_P      611680       // 49*49 = 2401
#define OFF_Q      614096       // 49*2401 = 117649 -> 731745
#define OFF_G      731760       // 7203
// end < 739000 floats = 2.96 MB

// weight of upsample(+reflect,+shift): output pixel p, shift sigma
__device__ __forceinline__ void wt_compute(int sigma, int p, int& i0c, int& i1c,
                                           float& w0, float& w1) {
  int k = p + sigma - 3;
  int r = k < 0 ? -k : (k > 223 ? 446 - k : k);    // np.pad 'reflect'
  float tc = (float)(2 * r - 31) * (1.0f / 64.0f); // (r+0.5)/32 - 0.5, exact
  float fl = floorf(tc);
  int i0 = (int)fl;
  float fr = tc - fl;
  i0c = min(max(i0, 0), 6);
  i1c = min(max(i0 + 1, 0), 6);
  w0 = 1.0f - fr;
  w1 = fr;
}

// blocks 0..146: feats; 147: WT; 148..276: V; 277..423: WW row i
__global__ void __launch_bounds__(256) k_initV(const float* __restrict__ x,
                                               const float* __restrict__ Wenc,
                                               float* __restrict__ ws) {
  __shared__ float red[4];
  __shared__ float rowI[512];
  int b = blockIdx.x;
  int t = threadIdx.x;
  if (b < NF) {
    int c = b / 49, rem = b % 49, cy = rem / 7, cx = rem % 7;
    float acc = 0.f;
    for (int idx = t; idx < 1024; idx += 256) {
      int yy = idx >> 5, xx = idx & 31;
      acc += x[(c * 224 + cy * 32 + yy) * 224 + cx * 32 + xx];
    }
    for (int off = 32; off; off >>= 1) acc += __shfl_down(acc, off);
    int wave = t >> 6, lane = t & 63;
    if (lane == 0) red[wave] = acc;
    __syncthreads();
    if (t == 0) ws[OFF_FEATS + b] = (red[0] + red[1] + red[2] + red[3]) * (1.0f / 1024.0f);
  } else if (b == NF) {
    float4* WT = (float4*)(ws + OFF_WT);
    for (int e = t; e < 7 * 224; e += 256) {
      int sigma = e / 224, p = e % 224;
      int i0c, i1c; float w0, w1;
      wt_compute(sigma, p, i0c, i1c, w0, w1);
      WT[e] = make_float4(w0, w1, __int_as_float(i0c), __int_as_float(i1c));
    }
  } else if (b < 277) {
    int tid = (b - NF - 1) * 256 + t;
    if (tid >= 7 * 3 * 224 * 7) return;
    int cx = tid % 7;
    int y  = (tid / 7) % 224;
    int c  = (tid / (7 * 224)) % 3;
    int sy = tid / (7 * 224 * 3);
    float acc[7];
    #pragma unroll
    for (int g = 0; g < 7; ++g) acc[g] = 0.f;
    const float* xrow = x + (c * 224 + y) * 224;
    for (int x0 = 0; x0 < 32; ++x0) {
      int px = cx * 32 + x0;
      int i0, i1; float w0, w1;
      wt_compute(sy, px, i0, i1, w0, w1);
      float v = xrow[px];
      #pragma unroll
      for (int g = 0; g < 7; ++g) {
        float w = (g == i0 ? w0 : 0.f) + (g == i1 ? w1 : 0.f);
        acc[g] = fmaf(w, v, acc[g]);
      }
    }
    float* Vp = ws + OFF_V + (((sy * 3 + c) * 224 + y) * 49 + cx * 7);
    #pragma unroll
    for (int g = 0; g < 7; ++g) Vp[g] = acc[g];
  } else {
    // WW[i][j] = Wenc row i . Wenc row j
    int i = b - 277;
    rowI[t] = Wenc[i * ND + t];
    rowI[t + 256] = Wenc[i * ND + t + 256];
    __syncthreads();
    if (t < NF) {
      const float* Wj = Wenc + t * ND;
      float a0 = 0.f, a1 = 0.f, a2 = 0.f, a3 = 0.f;
      for (int d = 0; d < ND; d += 4) {
        a0 = fmaf(rowI[d], Wj[d], a0);
        a1 = fmaf(rowI[d + 1], Wj[d + 1], a1);
        a2 = fmaf(rowI[d + 2], Wj[d + 2], a2);
        a3 = fmaf(rowI[d + 3], Wj[d + 3], a3);
      }
      ws[OFF_WW + i * NF + t] = (a0 + a1) + (a2 + a3);
    }
  }
}

// T2[sig][g][f]; tail threads zero G; last block computes w* = WW@feats, hsn
__global__ void __launch_bounds__(256) k_T(float* __restrict__ ws) {
  __shared__ float sFe[NF];
  __shared__ float sPr[NF];
  int b = blockIdx.x;
  int t = threadIdx.x;
  if (b == 1407) {
    if (t < NF) sFe[t] = ws[OFF_FEATS + t];
    __syncthreads();
    if (t < NF) {
      float acc = 0.f;
      for (int f = 0; f < NF; ++f)
        acc = fmaf(sFe[f], ws[OFF_WW + f * NF + t], acc);  // WW symmetric
      ws[OFF_WSTAR + t] = acc;
      sPr[t] = acc * sFe[t];
    }
    __syncthreads();
    if (t == 0) {
      float s = 0.f;
      for (int f = 0; f < NF; ++f) s += sPr[f];
      ws[OFF_HSN] = sqrtf(s);
    }
    return;
  }
  int tid = b * 256 + t;
  if (tid >= NSIG * NF * 49) {
    int e = tid - NSIG * NF * 49;
    if (e < 7203) ws[OFF_G + e] = 0.f;
    return;
  }
  int g = tid % 49;
  int f = (tid / 49) % NF;
  int sig = tid / (49 * NF);
  int sx = sig / 7, sy = sig % 7;
  int gy = g / 7, gx = g % 7;
  int c = f / 49, rem = f % 49, cy = rem / 7, cx = rem % 7;
  const float4* WT = (const float4*)(ws + OFF_WT);
  const float* V = ws + OFF_V + ((sy * 3 + c) * 224) * 49 + cx * 7 + gx;
  float acc = 0.f;
  for (int y0 = 0; y0 < 32; ++y0) {
    int y = cy * 32 + y0;
    float4 wt = WT[sx * 224 + y];
    int i0 = __float_as_int(wt.z), i1 = __float_as_int(wt.w);
    float w = (gy == i0 ? wt.x : 0.f) + (gy == i1 ? wt.y : 0.f);
    acc = fmaf(w, V[y * 49], acc);
  }
  ws[OFF_T + (sig * 49 + g) * NF + f] = acc * (1.0f / 1024.0f);
}

// per-(sig,half): A = T2s@WW (reg-tiled 5x3), Q = A@T2s^T, P = T2s@w*
__global__ void __launch_bounds__(256) k_AQP(float* __restrict__ ws) {
  __shared__ float sT2[49 * NF];   // 28.8 KB
  __shared__ float sA[25 * NF];    // 14.7 KB
  __shared__ float sWst[NF];
  int b = blockIdx.x;
  int sig = b >> 1, half = b & 1;
  int base = half ? 25 : 0;
  int nI = half ? 24 : 25;
  int t = threadIdx.x;
  const float* T2g = ws + OFF_T + sig * (49 * NF);
  for (int e = t; e < 49 * NF; e += 256) sT2[e] = T2g[e];
  if (t < NF) sWst[t] = ws[OFF_WSTAR + t];
  __syncthreads();
  // A-phase: 245 threads = 5 row-groups x 49 col-groups; 5 rows x 3 cols each
  if (t < 245) {
    int rg = t / 49, cg = t % 49;
    float acc[5][3];
    #pragma unroll
    for (int ri = 0; ri < 5; ++ri)
      #pragma unroll
      for (int ci = 0; ci < 3; ++ci) acc[ri][ci] = 0.f;
    const float* WWg = ws + OFF_WW + cg * 3;
    for (int f = 0; f < NF; ++f) {
      float wv0 = WWg[f * NF];
      float wv1 = WWg[f * NF + 1];
      float wv2 = WWg[f * NF + 2];
      #pragma unroll
      for (int ri = 0; ri < 5; ++ri) {
        int rl = rg * 5 + ri;
        int rc = rl < nI ? rl : nI - 1;
        float tv = sT2[(base + rc) * NF + f];
        acc[ri][0] = fmaf(tv, wv0, acc[ri][0]);
        acc[ri][1] = fmaf(tv, wv1, acc[ri][1]);
        acc[ri][2] = fmaf(tv, wv2, acc[ri][2]);
      }
    }
    #pragma unroll
    for (int ri = 0; ri < 5; ++ri) {
      int rl = rg * 5 + ri;
      if (rl < nI) {
        sA[rl * NF + cg * 3]     = acc[ri][0];
        sA[rl * NF + cg * 3 + 1] = acc[ri][1];
        sA[rl * NF + cg * 3 + 2] = acc[ri][2];
      }
    }
  }
  __syncthreads();
  // Q-phase: thread -> (local row il, l-group of 5)
  if (t < nI * 10) {
    int il = t / 10, lg = t % 10;
    float q[5] = {0.f, 0.f, 0.f, 0.f, 0.f};
    for (int f = 0; f < NF; ++f) {
      float av = sA[il * NF + f];
      #pragma unroll
      for (int qq = 0; qq < 5; ++qq) {
        int l = lg * 5 + qq; l = l < 49 ? l : 48;
        q[qq] = fmaf(av, sT2[l * NF + f], q[qq]);
      }
    }
    #pragma unroll
    for (int qq = 0; qq < 5; ++qq) {
      int l = lg * 5 + qq;
      if (l < 49) ws[OFF_Q + sig * 2401 + (base + il) * 49 + l] = q[qq];
    }
  }
  // P-phase
  if (t < nI) {
    float p = 0.f;
    for (int f = 0; f < NF; ++f)
      p = fmaf(sT2[(base + t) * NF + f], sWst[f], p);
    ws[OFF_P + sig * 49 + base + t] = p;
  }
}

// per-sample sims from P/Q, then coalesced atomic flush into G
__global__ void __launch_bounds__(256) k_S(const float* __restrict__ grids,
                                           const int* __restrict__ shx,
                                           const int* __restrict__ shy,
                                           float* __restrict__ ws) {
  __shared__ float sGr[NSAMP * 49];
  __shared__ int   sSig[NSAMP];
  __shared__ float sS[NSAMP];
  int b = blockIdx.x;
  int t = threadIdx.x;
  int i0s = b * NSAMP;
  for (int e = t; e < NSAMP * 49; e += 256) sGr[e] = grids[i0s * 49 + e];
  if (t < NSAMP) sSig[t] = shx[i0s + t] * 7 + shy[i0s + t];
  __syncthreads();
  int wave = t >> 6, lane = t & 63;
  float hsn = ws[OFF_HSN];
  for (int qs = 0; qs < 3; ++qs) {
    int r = wave * 3 + qs;
    int sig = sSig[r];
    const float* gr = sGr + r * 49;
    float np = (lane < 49) ? ws[OFF_P + sig * 49 + lane] * gr[lane] : 0.f;
    float sp = 0.f;
    const float* Qs = ws + OFF_Q + sig * 2401;
    for (int e = lane; e < 2401; e += 64) {
      int k = e / 49, l = e - k * 49;
      sp = fmaf(gr[k] * gr[l], Qs[e], sp);
    }
    for (int off = 32; off; off >>= 1) {
      np += __shfl_down(np, off);
      sp += __shfl_down(sp, off);
    }
    if (lane == 0) {
      float den = fmaxf(hsn * sqrtf(sp), 1e-8f);
      sS[r] = np / den;
    }
  }
  __syncthreads();
  // flush 12 samples into G; k-fastest lanes -> coalesced 49-address runs
  for (int e = t; e < NSAMP * 3 * 49; e += 256) {
    int k = e % 49;
    int rp = e / 49;
    int r = rp / 3, p = rp - r * 3;
    float gv = sGr[r * 49 + k];
    if (gv != 0.f) {
      float s = sS[r];
      float add = (p == 0) ? 1.f : ((p == 1) ? s : s * s);
      atomicAdd(&ws[OFF_G + p * 2401 + sSig[r] * 49 + k], add);
    }
  }
}

// per-px-column C slice + final Welford output (one block per px)
__global__ void __launch_bounds__(256) k_CO(const float* __restrict__ ws,
                                            float* __restrict__ out) {
  __shared__ float Gl[3 * 2401];
  __shared__ float sC[NF];          // [k][sx][gy]
  int b = blockIdx.x;               // px
  int t = threadIdx.x;
  for (int e = t; e < 3 * 2401; e += 256) Gl[e] = ws[OFF_G + e];
  __syncthreads();
  const float4* WT = (const float4*)(ws + OFF_WT);
  if (t < NF) {
    int k = t / 49, r = t - k * 49;
    int sx = r / 7, gy = r % 7;
    float acc = 0.f;
    for (int sy = 0; sy < 7; ++sy) {
      float4 wt = WT[sy * 224 + b];
      int i0 = __float_as_int(wt.z), i1 = __float_as_int(wt.w);
      int base = k * 2401 + (sx * 7 + sy) * 49 + gy * 7;
      acc += wt.x * Gl[base + i0] + wt.y * Gl[base + i1];
    }
    sC[t] = acc;
  }
  __syncthreads();
  if (t < 224) {
    int py = t;
    float S0 = 0.f, S1 = 0.f, S2 = 0.f;
    for (int sx = 0; sx < 7; ++sx) {
      float4 wt = WT[sx * 224 + py];
      int i0 = __float_as_int(wt.z), i1 = __float_as_int(wt.w);
      int base = sx * 7;
      S0 += wt.x * sC[base + i0]      + wt.y * sC[base + i1];
      S1 += wt.x * sC[49 + base + i0] + wt.y * sC[49 + base + i1];
      S2 += wt.x * sC[98 + base + i0] + wt.y * sC[98 + base + i1];
    }
    float W = 1e-10f + S0;
    float R = S1 / W;
    float U = S2 - S1 * S1 / W;
    out[py * 224 + b] = R;
    out[224 * 224 + py * 224 + b] = U / (W - 1.0f);
  }
}

extern "C" void kernel_launch(void* const* d_in, const int* in_sizes, int n_in,
                              void* d_out, int out_size, void* d_ws, size_t ws_size,
                              hipStream_t stream) {
  const float* x     = (const float*)d_in[0];
  const float* Wenc  = (const float*)d_in[1];
  const float* grids = (const float*)d_in[2];
  const int*   shx   = (const int*)d_in[3];
  const int*   shy   = (const int*)d_in[4];
  float* out = (float*)d_out;
  float* ws  = (float*)d_ws;

  k_initV<<<277 + NF, 256, 0, stream>>>(x, Wenc, ws);    // 424 blocks
  k_T<<<1408, 256, 0, stream>>>(ws);                     // T + zero G + w*
  k_AQP<<<NSIG * 2, 256, 0, stream>>>(ws);               // 98 blocks
  k_S<<<NSBLK, 256, 0, stream>>>(grids, shx, shy, ws);   // 250 blocks
  k_CO<<<224, 256, 0, stream>>>(ws, out);
}

// Round 9
// 153.177 us; speedup vs baseline: 1.0062x; 1.0062x over previous
//
#include <hip/hip_runtime.h>
#include <math.h>

// ---------------- problem constants ----------------
#define NS 3000          // 30*100 samples
#define NF 147           // 3*7*7 encoder feats
#define ND 512
#define NSIG 49          // 7x7 shift classes
#define NSAMP 12         // samples per k_S block
#define NSBLK 250        // 3000 / 12
#define WPAD 516         // panel row stride (16B-aligned, 2-way-bank-free)

// ---------------- ws layout (float offsets) ----------------
#define OFF_WT     0            // 6272 (7*224 float4: w0,w1,i0,i1)
#define OFF_FEATS  6272         // 147 -> pad 160
#define OFF_HSN    6432         // 1  -> pad 16
#define OFF_WW     6448         // 147*147 = 21609 -> pad to 28064
#define OFF_WSTAR  28064        // 147 -> pad 160
#define OFF_V      28224        // 7*3*224*49 = 230496 -> 258720
#define OFF_T      258720       // T2[sig][g][f]: 49*49*147 = 352947 -> 611667
#define OFF_P      611680       // 49*49 = 2401
#define OFF_Q      614096       // 49*2401 = 117649 -> 731745
#define OFF_G      731760       // 7203
// end < 739000 floats = 2.96 MB

// weight of upsample(+reflect,+shift): output pixel p, shift sigma
__device__ __forceinline__ void wt_compute(int sigma, int p, int& i0c, int& i1c,
                                           float& w0, float& w1) {
  int k = p + sigma - 3;
  int r = k < 0 ? -k : (k > 223 ? 446 - k : k);    // np.pad 'reflect'
  float tc = (float)(2 * r - 31) * (1.0f / 64.0f); // (r+0.5)/32 - 0.5, exact
  float fl = floorf(tc);
  int i0 = (int)fl;
  float fr = tc - fl;
  i0c = min(max(i0, 0), 6);
  i1c = min(max(i0 + 1, 0), 6);
  w0 = 1.0f - fr;
  w1 = fr;
}

// blocks 0..146: feats; 147: WT; 148..276: V; 277..376: WW 16x16 tiles
__global__ void __launch_bounds__(256) k_initV(const float* __restrict__ x,
                                               const float* __restrict__ Wenc,
                                               float* __restrict__ ws) {
  __shared__ float sP[2][16 * WPAD];   // 66 KB panels (WW branch)
  __shared__ float red[4];
  int b = blockIdx.x;
  int t = threadIdx.x;
  if (b < NF) {
    int c = b / 49, rem = b % 49, cy = rem / 7, cx = rem % 7;
    float acc = 0.f;
    for (int idx = t; idx < 1024; idx += 256) {
      int yy = idx >> 5, xx = idx & 31;
      acc += x[(c * 224 + cy * 32 + yy) * 224 + cx * 32 + xx];
    }
    for (int off = 32; off; off >>= 1) acc += __shfl_down(acc, off);
    int wave = t >> 6, lane = t & 63;
    if (lane == 0) red[wave] = acc;
    __syncthreads();
    if (t == 0) ws[OFF_FEATS + b] = (red[0] + red[1] + red[2] + red[3]) * (1.0f / 1024.0f);
  } else if (b == NF) {
    float4* WT = (float4*)(ws + OFF_WT);
    for (int e = t; e < 7 * 224; e += 256) {
      int sigma = e / 224, p = e % 224;
      int i0c, i1c; float w0, w1;
      wt_compute(sigma, p, i0c, i1c, w0, w1);
      WT[e] = make_float4(w0, w1, __int_as_float(i0c), __int_as_float(i1c));
    }
  } else if (b < 277) {
    int tid = (b - NF - 1) * 256 + t;
    if (tid >= 7 * 3 * 224 * 7) return;
    int cx = tid % 7;
    int y  = (tid / 7) % 224;
    int c  = (tid / (7 * 224)) % 3;
    int sy = tid / (7 * 224 * 3);
    float acc[7];
    #pragma unroll
    for (int g = 0; g < 7; ++g) acc[g] = 0.f;
    const float* xrow = x + (c * 224 + y) * 224;
    for (int x0 = 0; x0 < 32; ++x0) {
      int px = cx * 32 + x0;
      int i0, i1; float w0, w1;
      wt_compute(sy, px, i0, i1, w0, w1);
      float v = xrow[px];
      #pragma unroll
      for (int g = 0; g < 7; ++g) {
        float w = (g == i0 ? w0 : 0.f) + (g == i1 ? w1 : 0.f);
        acc[g] = fmaf(w, v, acc[g]);
      }
    }
    float* Vp = ws + OFF_V + (((sy * 3 + c) * 224 + y) * 49 + cx * 7);
    #pragma unroll
    for (int g = 0; g < 7; ++g) Vp[g] = acc[g];
  } else {
    // WW[gi][gj] 16x16 tile, LDS-staged coalesced panels
    int tb = b - 277;                 // 0..99
    int ti = tb / 10, tj = tb % 10;
    for (int e = t; e < 16 * ND; e += 256) {
      int r = e >> 9, d = e & 511;    // row in tile, depth
      int ri = min(ti * 16 + r, NF - 1);
      int rj = min(tj * 16 + r, NF - 1);
      sP[0][r * WPAD + d] = Wenc[ri * ND + d];
      sP[1][r * WPAD + d] = Wenc[rj * ND + d];
    }
    __syncthreads();
    int i = t >> 4, j = t & 15;
    const float4* pi4 = (const float4*)(sP[0] + i * WPAD);
    const float4* pj4 = (const float4*)(sP[1] + j * WPAD);
    float a0 = 0.f, a1 = 0.f, a2 = 0.f, a3 = 0.f;
    #pragma unroll 4
    for (int d4 = 0; d4 < ND / 4; ++d4) {
      float4 a = pi4[d4], bv = pj4[d4];
      a0 = fmaf(a.x, bv.x, a0);
      a1 = fmaf(a.y, bv.y, a1);
      a2 = fmaf(a.z, bv.z, a2);
      a3 = fmaf(a.w, bv.w, a3);
    }
    int gi = ti * 16 + i, gj = tj * 16 + j;
    if (gi < NF && gj < NF)
      ws[OFF_WW + gi * NF + gj] = (a0 + a1) + (a2 + a3);
  }
}

// T2[sig][g][f]; tail threads zero G; last block computes w* = WW@feats, hsn
__global__ void __launch_bounds__(256) k_T(float* __restrict__ ws) {
  __shared__ float sFe[NF];
  __shared__ float sPr[NF];
  int b = blockIdx.x;
  int t = threadIdx.x;
  if (b == 1407) {
    if (t < NF) sFe[t] = ws[OFF_FEATS + t];
    __syncthreads();
    if (t < NF) {
      float acc = 0.f;
      for (int f = 0; f < NF; ++f)
        acc = fmaf(sFe[f], ws[OFF_WW + f * NF + t], acc);  // WW symmetric
      ws[OFF_WSTAR + t] = acc;
      sPr[t] = acc * sFe[t];
    }
    __syncthreads();
    if (t == 0) {
      float s = 0.f;
      for (int f = 0; f < NF; ++f) s += sPr[f];
      ws[OFF_HSN] = sqrtf(s);
    }
    return;
  }
  int tid = b * 256 + t;
  if (tid >= NSIG * NF * 49) {
    int e = tid - NSIG * NF * 49;
    if (e < 7203) ws[OFF_G + e] = 0.f;
    return;
  }
  int g = tid % 49;
  int f = (tid / 49) % NF;
  int sig = tid / (49 * NF);
  int sx = sig / 7, sy = sig % 7;
  int gy = g / 7, gx = g % 7;
  int c = f / 49, rem = f % 49, cy = rem / 7, cx = rem % 7;
  const float4* WT = (const float4*)(ws + OFF_WT);
  const float* V = ws + OFF_V + ((sy * 3 + c) * 224) * 49 + cx * 7 + gx;
  float acc = 0.f;
  for (int y0 = 0; y0 < 32; ++y0) {
    int y = cy * 32 + y0;
    float4 wt = WT[sx * 224 + y];
    int i0 = __float_as_int(wt.z), i1 = __float_as_int(wt.w);
    float w = (gy == i0 ? wt.x : 0.f) + (gy == i1 ? wt.y : 0.f);
    acc = fmaf(w, V[y * 49], acc);
  }
  ws[OFF_T + (sig * 49 + g) * NF + f] = acc * (1.0f / 1024.0f);
}

// per-(sig,half): A = T2s@WW (reg-tiled 5x3), Q = A@T2s^T, P = T2s@w*
__global__ void __launch_bounds__(256) k_AQP(float* __restrict__ ws) {
  __shared__ float sT2[49 * NF];   // 28.8 KB
  __shared__ float sA[25 * NF];    // 14.7 KB
  __shared__ float sWst[NF];
  int b = blockIdx.x;
  int sig = b >> 1, half = b & 1;
  int base = half ? 25 : 0;
  int nI = half ? 24 : 25;
  int t = threadIdx.x;
  const float* T2g = ws + OFF_T + sig * (49 * NF);
  for (int e = t; e < 49 * NF; e += 256) sT2[e] = T2g[e];
  if (t < NF) sWst[t] = ws[OFF_WSTAR + t];
  __syncthreads();
  // A-phase: 245 threads = 5 row-groups x 49 col-groups; 5 rows x 3 cols each
  if (t < 245) {
    int rg = t / 49, cg = t % 49;
    float acc[5][3];
    #pragma unroll
    for (int ri = 0; ri < 5; ++ri)
      #pragma unroll
      for (int ci = 0; ci < 3; ++ci) acc[ri][ci] = 0.f;
    const float* WWg = ws + OFF_WW + cg * 3;
    for (int f = 0; f < NF; ++f) {
      float wv0 = WWg[f * NF];
      float wv1 = WWg[f * NF + 1];
      float wv2 = WWg[f * NF + 2];
      #pragma unroll
      for (int ri = 0; ri < 5; ++ri) {
        int rl = rg * 5 + ri;
        int rc = rl < nI ? rl : nI - 1;
        float tv = sT2[(base + rc) * NF + f];
        acc[ri][0] = fmaf(tv, wv0, acc[ri][0]);
        acc[ri][1] = fmaf(tv, wv1, acc[ri][1]);
        acc[ri][2] = fmaf(tv, wv2, acc[ri][2]);
      }
    }
    #pragma unroll
    for (int ri = 0; ri < 5; ++ri) {
      int rl = rg * 5 + ri;
      if (rl < nI) {
        sA[rl * NF + cg * 3]     = acc[ri][0];
        sA[rl * NF + cg * 3 + 1] = acc[ri][1];
        sA[rl * NF + cg * 3 + 2] = acc[ri][2];
      }
    }
  }
  __syncthreads();
  // Q-phase: thread -> (local row il, l-group of 5)
  if (t < nI * 10) {
    int il = t / 10, lg = t % 10;
    float q[5] = {0.f, 0.f, 0.f, 0.f, 0.f};
    for (int f = 0; f < NF; ++f) {
      float av = sA[il * NF + f];
      #pragma unroll
      for (int qq = 0; qq < 5; ++qq) {
        int l = lg * 5 + qq; l = l < 49 ? l : 48;
        q[qq] = fmaf(av, sT2[l * NF + f], q[qq]);
      }
    }
    #pragma unroll
    for (int qq = 0; qq < 5; ++qq) {
      int l = lg * 5 + qq;
      if (l < 49) ws[OFF_Q + sig * 2401 + (base + il) * 49 + l] = q[qq];
    }
  }
  // P-phase
  if (t < nI) {
    float p = 0.f;
    for (int f = 0; f < NF; ++f)
      p = fmaf(sT2[(base + t) * NF + f], sWst[f], p);
    ws[OFF_P + sig * 49 + base + t] = p;
  }
}

// per-sample sims from P/Q, then coalesced atomic flush into G
__global__ void __launch_bounds__(256) k_S(const float* __restrict__ grids,
                                           const int* __restrict__ shx,
                                           const int* __restrict__ shy,
                                           float* __restrict__ ws) {
  __shared__ float sGr[NSAMP * 49];
  __shared__ int   sSig[NSAMP];
  __shared__ float sS[NSAMP];
  int b = blockIdx.x;
  int t = threadIdx.x;
  int i0s = b * NSAMP;
  for (int e = t; e < NSAMP * 49; e += 256) sGr[e] = grids[i0s * 49 + e];
  if (t < NSAMP) sSig[t] = shx[i0s + t] * 7 + shy[i0s + t];
  __syncthreads();
  int wave = t >> 6, lane = t & 63;
  float hsn = ws[OFF_HSN];
  for (int qs = 0; qs < 3; ++qs) {
    int r = wave * 3 + qs;
    int sig = sSig[r];
    const float* gr = sGr + r * 49;
    float np = (lane < 49) ? ws[OFF_P + sig * 49 + lane] * gr[lane] : 0.f;
    float sp = 0.f;
    const float* Qs = ws + OFF_Q + sig * 2401;
    for (int e = lane; e < 2401; e += 64) {
      int k = e / 49, l = e - k * 49;
      sp = fmaf(gr[k] * gr[l], Qs[e], sp);
    }
    for (int off = 32; off; off >>= 1) {
      np += __shfl_down(np, off);
      sp += __shfl_down(sp, off);
    }
    if (lane == 0) {
      float den = fmaxf(hsn * sqrtf(sp), 1e-8f);
      sS[r] = np / den;
    }
  }
  __syncthreads();
  // flush 12 samples into G; k-fastest lanes -> coalesced 49-address runs
  for (int e = t; e < NSAMP * 3 * 49; e += 256) {
    int k = e % 49;
    int rp = e / 49;
    int r = rp / 3, p = rp - r * 3;
    float gv = sGr[r * 49 + k];
    if (gv != 0.f) {
      float s = sS[r];
      float add = (p == 0) ? 1.f : ((p == 1) ? s : s * s);
      atomicAdd(&ws[OFF_G + p * 2401 + sSig[r] * 49 + k], add);
    }
  }
}

// per-px-column C slice + final Welford output (one block per px)
__global__ void __launch_bounds__(256) k_CO(const float* __restrict__ ws,
                                            float* __restrict__ out) {
  __shared__ float Gl[3 * 2401];
  __shared__ float sC[NF];          // [k][sx][gy]
  int b = blockIdx.x;               // px
  int t = threadIdx.x;
  for (int e = t; e < 3 * 2401; e += 256) Gl[e] = ws[OFF_G + e];
  __syncthreads();
  const float4* WT = (const float4*)(ws + OFF_WT);
  if (t < NF) {
    int k = t / 49, r = t - k * 49;
    int sx = r / 7, gy = r % 7;
    float acc = 0.f;
    for (int sy = 0; sy < 7; ++sy) {
      float4 wt = WT[sy * 224 + b];
      int i0 = __float_as_int(wt.z), i1 = __float_as_int(wt.w);
      int base = k * 2401 + (sx * 7 + sy) * 49 + gy * 7;
      acc += wt.x * Gl[base + i0] + wt.y * Gl[base + i1];
    }
    sC[t] = acc;
  }
  __syncthreads();
  if (t < 224) {
    int py = t;
    float S0 = 0.f, S1 = 0.f, S2 = 0.f;
    for (int sx = 0; sx < 7; ++sx) {
      float4 wt = WT[sx * 224 + py];
      int i0 = __float_as_int(wt.z), i1 = __float_as_int(wt.w);
      int base = sx * 7;
      S0 += wt.x * sC[base + i0]      + wt.y * sC[base + i1];
      S1 += wt.x * sC[49 + base + i0] + wt.y * sC[49 + base + i1];
      S2 += wt.x * sC[98 + base + i0] + wt.y * sC[98 + base + i1];
    }
    float W = 1e-10f + S0;
    float R = S1 / W;
    float U = S2 - S1 * S1 / W;
    out[py * 224 + b] = R;
    out[224 * 224 + py * 224 + b] = U / (W - 1.0f);
  }
}

extern "C" void kernel_launch(void* const* d_in, const int* in_sizes, int n_in,
                              void* d_out, int out_size, void* d_ws, size_t ws_size,
                              hipStream_t stream) {
  const float* x     = (const float*)d_in[0];
  const float* Wenc  = (const float*)d_in[1];
  const float* grids = (const float*)d_in[2];
  const int*   shx   = (const int*)d_in[3];
  const int*   shy   = (const int*)d_in[4];
  float* out = (float*)d_out;
  float* ws  = (float*)d_ws;

  k_initV<<<377, 256, 0, stream>>>(x, Wenc, ws);         // feats+WT+V+WW
  k_T<<<1408, 256, 0, stream>>>(ws);                     // T + zero G + w*
  k_AQP<<<NSIG * 2, 256, 0, stream>>>(ws);               // 98 blocks
  k_S<<<NSBLK, 256, 0, stream>>>(grids, shx, shy, ws);   // 250 blocks
  k_CO<<<224, 256, 0, stream>>>(ws, out);
}

// Round 10
// 109.742 us; speedup vs baseline: 1.4044x; 1.3958x over previous
//
#include <hip/hip_runtime.h>
#include <math.h>

// ---------------- problem constants ----------------
#define NS 3000          // 30*100 samples
#define NF 147           // 3*7*7 encoder feats
#define ND 512
#define NSIG 49          // 7x7 shift classes
#define NSAMP 4          // samples per k_H2s block (750 blocks -> ~3/CU)
#define NHBLK 750        // 3000 / 4

// ---------------- ws layout (float offsets) ----------------
#define OFF_WT     0            // 6272 (7*224 float4: w0,w1,i0,i1)
#define OFF_FEATS  6272         // 160
#define OFF_V      6432         // 7*3*224*49 = 230496  -> ends 236928
#define OFF_T      236928       // T2[sig][g][f]: 49*49*147 = 352947 -> 589875
#define OFF_G      589952       // 7203
// end < 600240 floats = 2.4 MB

// weight of upsample(+reflect,+shift): output pixel p, shift sigma
__device__ __forceinline__ void wt_compute(int sigma, int p, int& i0c, int& i1c,
                                           float& w0, float& w1) {
  int k = p + sigma - 3;
  int r = k < 0 ? -k : (k > 223 ? 446 - k : k);    // np.pad 'reflect'
  float tc = (float)(2 * r - 31) * (1.0f / 64.0f); // (r+0.5)/32 - 0.5, exact
  float fl = floorf(tc);
  int i0 = (int)fl;
  float fr = tc - fl;
  i0c = min(max(i0, 0), 6);
  i1c = min(max(i0 + 1, 0), 6);
  w0 = 1.0f - fr;
  w1 = fr;
}

// blocks 0..146: h_star feats (32x32 block means); 147: WT table; 148+: V
__global__ void __launch_bounds__(256) k_initV(const float* __restrict__ x,
                                               float* __restrict__ ws) {
  int b = blockIdx.x;
  int t = threadIdx.x;
  if (b < NF) {
    int c = b / 49, rem = b % 49, cy = rem / 7, cx = rem % 7;
    float acc = 0.f;
    for (int idx = t; idx < 1024; idx += 256) {
      int yy = idx >> 5, xx = idx & 31;
      acc += x[(c * 224 + cy * 32 + yy) * 224 + cx * 32 + xx];
    }
    for (int off = 32; off; off >>= 1) acc += __shfl_down(acc, off);
    __shared__ float red[4];
    int wave = t >> 6, lane = t & 63;
    if (lane == 0) red[wave] = acc;
    __syncthreads();
    if (t == 0) ws[OFF_FEATS + b] = (red[0] + red[1] + red[2] + red[3]) * (1.0f / 1024.0f);
  } else if (b == NF) {
    float4* WT = (float4*)(ws + OFF_WT);
    for (int e = t; e < 7 * 224; e += 256) {
      int sigma = e / 224, p = e % 224;
      int i0c, i1c; float w0, w1;
      wt_compute(sigma, p, i0c, i1c, w0, w1);
      WT[e] = make_float4(w0, w1, __int_as_float(i0c), __int_as_float(i1c));
    }
  } else {
    int tid = (b - NF - 1) * 256 + t;
    if (tid >= 7 * 3 * 224 * 7) return;
    int cx = tid % 7;
    int y  = (tid / 7) % 224;
    int c  = (tid / (7 * 224)) % 3;
    int sy = tid / (7 * 224 * 3);
    float acc[7];
    #pragma unroll
    for (int g = 0; g < 7; ++g) acc[g] = 0.f;
    const float* xrow = x + (c * 224 + y) * 224;
    for (int x0 = 0; x0 < 32; ++x0) {
      int px = cx * 32 + x0;
      int i0, i1; float w0, w1;
      wt_compute(sy, px, i0, i1, w0, w1);   // inline (no dep on WT block)
      float v = xrow[px];
      #pragma unroll
      for (int g = 0; g < 7; ++g) {
        float w = (g == i0 ? w0 : 0.f) + (g == i1 ? w1 : 0.f);
        acc[g] = fmaf(w, v, acc[g]);
      }
    }
    float* Vp = ws + OFF_V + (((sy * 3 + c) * 224 + y) * 49 + cx * 7);
    #pragma unroll
    for (int g = 0; g < 7; ++g) Vp[g] = acc[g];
  }
}

// T2[sig][g][f] = (1/1024) sum_{y in cy-block} wy(y,gy;sx) * V[sy][c][y][cx][gx]
// tail threads zero G for k_H2s's atomics
__global__ void __launch_bounds__(256) k_T(float* __restrict__ ws) {
  int tid = blockIdx.x * blockDim.x + threadIdx.x;
  if (tid >= NSIG * NF * 49) {
    int e = tid - NSIG * NF * 49;
    if (e < 7203) ws[OFF_G + e] = 0.f;
    return;
  }
  int g = tid % 49;
  int f = (tid / 49) % NF;
  int sig = tid / (49 * NF);
  int sx = sig / 7, sy = sig % 7;
  int gy = g / 7, gx = g % 7;
  int c = f / 49, rem = f % 49, cy = rem / 7, cx = rem % 7;
  const float4* WT = (const float4*)(ws + OFF_WT);
  const float* V = ws + OFF_V + ((sy * 3 + c) * 224) * 49 + cx * 7 + gx;
  float acc = 0.f;
  for (int y0 = 0; y0 < 32; ++y0) {
    int y = cy * 32 + y0;
    float4 wt = WT[sx * 224 + y];
    int i0 = __float_as_int(wt.z), i1 = __float_as_int(wt.w);
    float w = (gy == i0 ? wt.x : 0.f) + (gy == i1 ? wt.y : 0.f);
    acc = fmaf(w, V[y * 49], acc);
  }
  ws[OFF_T + (sig * 49 + g) * NF + f] = acc * (1.0f / 1024.0f);
}

// fused: F = T2[sig]@g (LDS), h* col + H = F@Wenc one pass, s_i in LDS,
// then per-sample coalesced atomic flush into global G (k-fastest lanes)
// NSAMP=4 -> 750 blocks for ~3 blocks/CU occupancy (R7 ran 250 @ 1/CU)
__global__ void __launch_bounds__(256) k_H2s(const float* __restrict__ Wenc,
                                             const float* __restrict__ grids,
                                             const int* __restrict__ shx,
                                             const int* __restrict__ shy,
                                             float* __restrict__ ws) {
  __shared__ __align__(16) float sF[NF * NSAMP];  // [f][r], float4 per f
  __shared__ float sGr[NSAMP * 49];               // [r][g]
  __shared__ float sFeat[NF];
  __shared__ int   sSig[NSAMP];
  __shared__ float sRed[2][NSAMP][4];
  __shared__ float sRedH[4];
  __shared__ float sS[NSAMP];
  int t = threadIdx.x;
  int b = blockIdx.x;
  int i0s = b * NSAMP;
  for (int e = t; e < NSAMP * 49; e += 256) sGr[e] = grids[i0s * 49 + e];
  if (t < NSAMP) sSig[t] = shx[i0s + t] * 7 + shy[i0s + t];
  if (t < NF) sFeat[t] = ws[OFF_FEATS + t];
  __syncthreads();
  for (int idx = t; idx < NF * NSAMP; idx += 256) {
    int r = idx / NF, f = idx - r * NF;
    const float* T2 = ws + OFF_T + sSig[r] * (49 * NF) + f;
    const float* gr = sGr + r * 49;
    float acc = 0.f;
    #pragma unroll
    for (int g = 0; g < 49; ++g) acc = fmaf(T2[g * NF], gr[g], acc);
    sF[f * NSAMP + r] = acc;
  }
  __syncthreads();
  float accA[NSAMP], accB[NSAMP];
  #pragma unroll
  for (int r = 0; r < NSAMP; ++r) { accA[r] = 0.f; accB[r] = 0.f; }
  float h0 = 0.f, h1 = 0.f;
  const float* W0 = Wenc + t;
  const float* W1 = Wenc + t + 256;
  const float4* sF4 = (const float4*)sF;
  for (int f = 0; f < NF; ++f) {
    float w0 = W0[f * ND];
    float w1 = W1[f * ND];
    float fe = sFeat[f];
    h0 = fmaf(fe, w0, h0);
    h1 = fmaf(fe, w1, h1);
    float4 a4 = sF4[f];
    float a[NSAMP] = {a4.x, a4.y, a4.z, a4.w};
    #pragma unroll
    for (int r = 0; r < NSAMP; ++r) {
      accA[r] = fmaf(a[r], w0, accA[r]);
      accB[r] = fmaf(a[r], w1, accB[r]);
    }
  }
  int wave = t >> 6, lane = t & 63;
  float hq = h0 * h0 + h1 * h1;
  for (int off = 32; off; off >>= 1) hq += __shfl_down(hq, off);
  if (lane == 0) sRedH[wave] = hq;
  #pragma unroll
  for (int r = 0; r < NSAMP; ++r) {
    float np = accA[r] * h0 + accB[r] * h1;
    float sp = accA[r] * accA[r] + accB[r] * accB[r];
    for (int off = 32; off; off >>= 1) {
      np += __shfl_down(np, off);
      sp += __shfl_down(sp, off);
    }
    if (lane == 0) { sRed[0][r][wave] = np; sRed[1][r][wave] = sp; }
  }
  __syncthreads();
  if (t == 0) sRedH[0] = sqrtf(sRedH[0] + sRedH[1] + sRedH[2] + sRedH[3]);
  __syncthreads();
  if (t < NSAMP) {
    float np = sRed[0][t][0] + sRed[0][t][1] + sRed[0][t][2] + sRed[0][t][3];
    float sp = sRed[1][t][0] + sRed[1][t][1] + sRed[1][t][2] + sRed[1][t][3];
    float den = fmaxf(sRedH[0] * sqrtf(sp), 1e-8f);
    sS[t] = np / den;
  }
  __syncthreads();
  // flush this block's samples into G; k-fastest lanes -> coalesced runs
  for (int e = t; e < NSAMP * 3 * 49; e += 256) {
    int k = e % 49;
    int rp = e / 49;
    int r = rp / 3, p = rp - r * 3;
    float gv = sGr[r * 49 + k];
    if (gv != 0.f) {
      float s = sS[r];
      float add = (p == 0) ? 1.f : ((p == 1) ? s : s * s);
      atomicAdd(&ws[OFF_G + p * 2401 + sSig[r] * 49 + k], add);
    }
  }
}

// per-px-column C slice + final Welford output (one block per px)
__global__ void __launch_bounds__(256) k_CO(const float* __restrict__ ws,
                                            float* __restrict__ out) {
  __shared__ float Gl[3 * 2401];
  __shared__ float sC[NF];          // [k][sx][gy]
  int b = blockIdx.x;               // px
  int t = threadIdx.x;
  for (int e = t; e < 3 * 2401; e += 256) Gl[e] = ws[OFF_G + e];
  __syncthreads();
  const float4* WT = (const float4*)(ws + OFF_WT);
  if (t < NF) {
    int k = t / 49, r = t - k * 49;
    int sx = r / 7, gy = r % 7;
    float acc = 0.f;
    for (int sy = 0; sy < 7; ++sy) {
      float4 wt = WT[sy * 224 + b];
      int i0 = __float_as_int(wt.z), i1 = __float_as_int(wt.w);
      int base = k * 2401 + (sx * 7 + sy) * 49 + gy * 7;
      acc += wt.x * Gl[base + i0] + wt.y * Gl[base + i1];
    }
    sC[t] = acc;
  }
  __syncthreads();
  if (t < 224) {
    int py = t;
    float S0 = 0.f, S1 = 0.f, S2 = 0.f;
    for (int sx = 0; sx < 7; ++sx) {
      float4 wt = WT[sx * 224 + py];
      int i0 = __float_as_int(wt.z), i1 = __float_as_int(wt.w);
      int base = sx * 7;
      S0 += wt.x * sC[base + i0]      + wt.y * sC[base + i1];
      S1 += wt.x * sC[49 + base + i0] + wt.y * sC[49 + base + i1];
      S2 += wt.x * sC[98 + base + i0] + wt.y * sC[98 + base + i1];
    }
    float W = 1e-10f + S0;
    float R = S1 / W;
    float U = S2 - S1 * S1 / W;
    out[py * 224 + b] = R;
    out[224 * 224 + py * 224 + b] = U / (W - 1.0f);
  }
}

extern "C" void kernel_launch(void* const* d_in, const int* in_sizes, int n_in,
                              void* d_out, int out_size, void* d_ws, size_t ws_size,
                              hipStream_t stream) {
  const float* x     = (const float*)d_in[0];
  const float* Wenc  = (const float*)d_in[1];
  const float* grids = (const float*)d_in[2];
  const int*   shx   = (const int*)d_in[3];
  const int*   shy   = (const int*)d_in[4];
  float* out = (float*)d_out;
  float* ws  = (float*)d_ws;

  int vblocks = (7 * 3 * 224 * 7 + 255) / 256;           // 129
  k_initV<<<NF + 1 + vblocks, 256, 0, stream>>>(x, ws);  // 277 blocks
  // 1379 work blocks + tail threads for G zeroing
  k_T<<<(NSIG * NF * 49 + 7203 + 255) / 256, 256, 0, stream>>>(ws);
  k_H2s<<<NHBLK, 256, 0, stream>>>(Wenc, grids, shx, shy, ws);
  k_CO<<<224, 256, 0, stream>>>(ws, out);
}